// Round 1
// baseline (272.858 us; speedup 1.0000x reference)
//
#include <hip/hip_runtime.h>

// Problem constants (from reference setup_inputs)
constexpr int T  = 16384;  // tokens
constexpr int HD = 4096;   // hidden dim
constexpr int E  = 64;     // experts

constexpr int BM = 32;     // rows per block
constexpr int BK = 32;     // k-chunk

// ---------------------------------------------------------------------------
// Kernel 1: router logits GEMM  logits[T,E] = H[T,HD] x W[E,HD]^T  (fp32)
// Block: 256 threads (4 waves). Tile BM=32 rows x all 64 experts, BK=32.
// Each thread computes a 2x4 micro-tile (rows ty+{0,16}, cols tx+{0,16,32,48}).
// ---------------------------------------------------------------------------
__global__ __launch_bounds__(256) void router_gemm(const float* __restrict__ H,
                                                   const float* __restrict__ W,
                                                   float* __restrict__ logits) {
  __shared__ float As[BK][BM + 1];  // k-major, +1 pad
  __shared__ float Bs[BK][E + 1];   // k-major, +1 pad

  const int tid  = threadIdx.x;
  const int row0 = blockIdx.x * BM;
  const int tx   = tid & 15;   // expert sub-index
  const int ty   = tid >> 4;   // row sub-index 0..15

  // staging indices
  const int ar  = tid & 31;    // row within A tile
  const int ac4 = tid >> 5;    // float4 group 0..7
  const int be  = tid & 63;    // expert row of W
  const int bc4 = tid >> 6;    // float4 group 0..3 (plus +4 on 2nd pass)

  float acc[2][4] = {{0.f, 0.f, 0.f, 0.f}, {0.f, 0.f, 0.f, 0.f}};

  for (int k0 = 0; k0 < HD; k0 += BK) {
    // stage A: 32 rows x 32 k = 1024 floats, 1 float4/thread, transpose to k-major
    {
      float4 v = *reinterpret_cast<const float4*>(H + (size_t)(row0 + ar) * HD + k0 + 4 * ac4);
      As[4 * ac4 + 0][ar] = v.x;
      As[4 * ac4 + 1][ar] = v.y;
      As[4 * ac4 + 2][ar] = v.z;
      As[4 * ac4 + 3][ar] = v.w;
    }
    // stage B: 64 experts x 32 k = 2048 floats, 2 float4/thread
#pragma unroll
    for (int hh = 0; hh < 2; ++hh) {
      const int cc = bc4 + 4 * hh;
      float4 v = *reinterpret_cast<const float4*>(W + (size_t)be * HD + k0 + 4 * cc);
      Bs[4 * cc + 0][be] = v.x;
      Bs[4 * cc + 1][be] = v.y;
      Bs[4 * cc + 2][be] = v.z;
      Bs[4 * cc + 3][be] = v.w;
    }
    __syncthreads();

#pragma unroll
    for (int k = 0; k < BK; ++k) {
      const float a0 = As[k][ty];
      const float a1 = As[k][ty + 16];
      const float b0 = Bs[k][tx];
      const float b1 = Bs[k][tx + 16];
      const float b2 = Bs[k][tx + 32];
      const float b3 = Bs[k][tx + 48];
      acc[0][0] += a0 * b0; acc[0][1] += a0 * b1; acc[0][2] += a0 * b2; acc[0][3] += a0 * b3;
      acc[1][0] += a1 * b0; acc[1][1] += a1 * b1; acc[1][2] += a1 * b2; acc[1][3] += a1 * b3;
    }
    __syncthreads();
  }

#pragma unroll
  for (int i = 0; i < 2; ++i) {
    const int r = row0 + ty + 16 * i;
#pragma unroll
    for (int j = 0; j < 4; ++j) {
      logits[(size_t)r * E + tx + 16 * j] = acc[i][j];
    }
  }
}

// ---------------------------------------------------------------------------
// Kernel 2: per-row softmax + top-2 (+renorm). One wave per row, lane=expert.
// ---------------------------------------------------------------------------
__global__ __launch_bounds__(256) void router_topk(const float* __restrict__ logits,
                                                   float* __restrict__ topw,
                                                   float* __restrict__ topi) {
  const int tid  = threadIdx.x;
  const int lane = tid & 63;
  const int row  = blockIdx.x * 4 + (tid >> 6);

  const float x = logits[(size_t)row * E + lane];

  // softmax (fp32)
  float m = x;
#pragma unroll
  for (int off = 32; off; off >>= 1) m = fmaxf(m, __shfl_xor(m, off));
  const float p = expf(x - m);
  float s = p;
#pragma unroll
  for (int off = 32; off; off >>= 1) s += __shfl_xor(s, off);
  const float prob = p / s;

  // top-1 (max value, min index on tie — matches lax.top_k)
  float v1 = prob;
  int   i1 = lane;
#pragma unroll
  for (int off = 32; off; off >>= 1) {
    const float ov = __shfl_xor(v1, off);
    const int   oi = __shfl_xor(i1, off);
    if (ov > v1 || (ov == v1 && oi < i1)) { v1 = ov; i1 = oi; }
  }
  // top-2: mask out i1, reduce again
  float v2 = (lane == i1) ? -1.0f : prob;  // probs are >= 0
  int   i2 = lane;
#pragma unroll
  for (int off = 32; off; off >>= 1) {
    const float ov = __shfl_xor(v2, off);
    const int   oi = __shfl_xor(i2, off);
    if (ov > v2 || (ov == v2 && oi < i2)) { v2 = ov; i2 = oi; }
  }

  if (lane == 0) {
    const float sum = v1 + v2;
    topw[(size_t)row * 2 + 0] = v1 / sum;
    topw[(size_t)row * 2 + 1] = v2 / sum;
    topi[(size_t)row * 2 + 0] = (float)i1;
    topi[(size_t)row * 2 + 1] = (float)i2;
  }
}

extern "C" void kernel_launch(void* const* d_in, const int* in_sizes, int n_in,
                              void* d_out, int out_size, void* d_ws, size_t ws_size,
                              hipStream_t stream) {
  const float* H = (const float*)d_in[0];  // [16384, 4096] fp32
  const float* W = (const float*)d_in[1];  // [64, 4096] fp32

  float* out    = (float*)d_out;
  float* topw   = out;                       // [16384, 2]
  float* logits = out + (size_t)T * 2;       // [16384, 64]
  float* topi   = logits + (size_t)T * E;    // [16384, 2] (indices as float)

  router_gemm<<<T / BM, 256, 0, stream>>>(H, W, logits);
  router_topk<<<T / 4, 256, 0, stream>>>(logits, topw, topi);
}

// Round 2
// 83.587 us; speedup vs baseline: 3.2644x; 3.2644x over previous
//
#include <hip/hip_runtime.h>

constexpr int T  = 16384;  // tokens
constexpr int HD = 4096;   // hidden dim
constexpr int E  = 64;     // experts
constexpr int BK = 32;     // k per chunk
constexpr int NCH = HD / BK;  // 128 chunks

using short8 = __attribute__((ext_vector_type(8))) short;
using f32x4  = __attribute__((ext_vector_type(4))) float;

#define AS1 __attribute__((address_space(1)))
#define AS3 __attribute__((address_space(3)))

__device__ __forceinline__ unsigned short f2bf(float x) {
  union { float f; unsigned u; } v; v.f = x;
  return (unsigned short)((v.u + 0x7FFFu + ((v.u >> 16) & 1u)) >> 16);
}
__device__ __forceinline__ float bf2f(unsigned short h) {
  union { float f; unsigned u; } v; v.u = ((unsigned)h) << 16;
  return v.f;
}

__device__ __forceinline__ void gload16(const void* g, void* l) {
  __builtin_amdgcn_global_load_lds((const AS1 void*)g, (AS3 void*)l, 16, 0, 0);
}

// ---------------------------------------------------------------------------
// Kernel 0: convert W (fp32 [64][4096]) into the bf16 hi/lo packed, XOR-swizzled
// LDS image in ws. Layout: [chunk 128][expert 64][slot' 8] x 16B, where
// slot' = slot ^ (e&7); slot<4: hi part k-local [slot*8..+8), slot>=4: lo part.
// ---------------------------------------------------------------------------
__global__ __launch_bounds__(256) void wprep(const float* __restrict__ W,
                                             short* __restrict__ img) {
  const int tid = blockIdx.x * 256 + threadIdx.x;   // 0..65535
  const int c   = tid >> 9;          // chunk
  const int rem = tid & 511;
  const int e   = rem >> 3;          // expert
  const int sp  = rem & 7;           // stored (swizzled) slot
  const int s   = sp ^ (e & 7);      // logical slot
  const int part = s >> 2;           // 0 = hi, 1 = lo
  const int sl  = s & 3;             // k-group within chunk
  const float* src = W + (size_t)e * HD + c * BK + sl * 8;
  short8 v;
#pragma unroll
  for (int j = 0; j < 8; ++j) {
    float x = src[j];
    unsigned short h = f2bf(x);
    v[j] = part ? (short)f2bf(x - bf2f(h)) : (short)h;
  }
  *(short8*)(img + (size_t)tid * 8) = v;   // tid*16B == c*8192 + e*128 + sp*16
}

// ---------------------------------------------------------------------------
// Kernel 1: logits[T,64] = H[T,4096] x W^T via split-bf16 MFMA.
// 256 blocks x 256 threads (4 waves). Wave w: rows 16w..16w+15, all 64 experts
// as 4 16x16 col-tiles. BK=32 per chunk, pure global_load_lds staging:
// A fp32 triple-buffered (depth-2 HBM prefetch), B image double-buffered (L2).
// Counted vmcnt(2) + raw s_barrier; no vmcnt(0) drain in main loop.
// ---------------------------------------------------------------------------
__global__ __launch_bounds__(256) void router_gemm(const float* __restrict__ H,
                                                   const short* __restrict__ wsB,
                                                   float* __restrict__ logits) {
  __shared__ __align__(16) char lds_raw[3 * 8192 + 2 * 8192];  // A x3, B x2

  const int tid  = threadIdx.x;
  const int w    = tid >> 6;
  const int lane = tid & 63;
  const int q    = lane >> 4;   // 0..3
  const int r    = lane & 15;
  const int row0 = blockIdx.x * 64;

  f32x4 acc[4];
#pragma unroll
  for (int ct = 0; ct < 4; ++ct)
#pragma unroll
    for (int i = 0; i < 4; ++i) acc[ct][i] = 0.f;

  // --- staging (per wave: 2 DMA for A rows 16w..16w+15, 2 DMA for B) ---
  auto stageA = [&](int chunk, int abuf) {
    char* dst = lds_raw + abuf * 8192 + w * 2048;
#pragma unroll
    for (int j = 0; j < 2; ++j) {
      const int rl = 8 * j + (lane >> 3);       // row-local 0..15
      const int R  = 16 * w + rl;               // block row
      const int s  = (lane & 7) ^ (R & 7);      // pre-swizzled source slot
      const char* src = (const char*)H + ((size_t)(row0 + R) * HD + chunk * BK) * 4 + s * 16;
      gload16(src, dst + j * 1024);
    }
  };
  auto stageB = [&](int chunk, int bbuf) {
    char* dst = lds_raw + 24576 + bbuf * 8192 + w * 2048;
    const char* src = (const char*)wsB + (size_t)chunk * 8192 + w * 2048 + lane * 16;
    gload16(src, dst);
    gload16(src + 1024, dst + 1024);
  };

  const int Rrow = 16 * w + r;
  const int ra   = Rrow & 7;

  auto compute = [&](int abuf, int bbuf) {
    const char* Ar = lds_raw + abuf * 8192 + Rrow * 128;
    const char* Bb = lds_raw + 24576 + bbuf * 8192;
    f32x4 a0 = *(const f32x4*)(Ar + ((2 * q) ^ ra) * 16);
    f32x4 a1 = *(const f32x4*)(Ar + ((2 * q + 1) ^ ra) * 16);
    short8 ahi, alo;
#pragma unroll
    for (int jj = 0; jj < 4; ++jj) {
      unsigned short h0 = f2bf(a0[jj]);
      ahi[jj] = (short)h0; alo[jj] = (short)f2bf(a0[jj] - bf2f(h0));
      unsigned short h1 = f2bf(a1[jj]);
      ahi[4 + jj] = (short)h1; alo[4 + jj] = (short)f2bf(a1[jj] - bf2f(h1));
    }
#pragma unroll
    for (int ct = 0; ct < 4; ++ct) {
      const int e = 16 * ct + r;
      const char* Br = Bb + e * 128;
      short8 bhi = *(const short8*)(Br + ((q) ^ (e & 7)) * 16);
      short8 blo = *(const short8*)(Br + ((4 + q) ^ (e & 7)) * 16);
      acc[ct] = __builtin_amdgcn_mfma_f32_16x16x32_bf16(ahi, bhi, acc[ct], 0, 0, 0);
      acc[ct] = __builtin_amdgcn_mfma_f32_16x16x32_bf16(alo, bhi, acc[ct], 0, 0, 0);
      acc[ct] = __builtin_amdgcn_mfma_f32_16x16x32_bf16(ahi, blo, acc[ct], 0, 0, 0);
    }
  };

  // --- prologue: issue order matters for in-order vmcnt accounting ---
  stageA(0, 0);      // oldest
  stageB(0, 0);
  stageA(1, 1);

  int ab = 0, bb = 0;
  for (int t = 0; t < NCH - 2; ++t) {
    asm volatile("s_waitcnt vmcnt(2)\n\ts_barrier" ::: "memory");  // A(t),B(t) done; A(t+1) flying
    stageB(t + 1, bb ^ 1);
    int ab2 = ab + 2; if (ab2 >= 3) ab2 -= 3;
    stageA(t + 2, ab2);
    compute(ab, bb);
    ab = (ab == 2) ? 0 : ab + 1;
    bb ^= 1;
  }
  // t = NCH-2
  asm volatile("s_waitcnt vmcnt(2)\n\ts_barrier" ::: "memory");
  stageB(NCH - 1, bb ^ 1);
  compute(ab, bb);
  ab = (ab == 2) ? 0 : ab + 1;
  bb ^= 1;
  // t = NCH-1
  asm volatile("s_waitcnt vmcnt(0)\n\ts_barrier" ::: "memory");
  compute(ab, bb);

  // --- epilogue: D layout col = lane&15, row = 4*(lane>>4)+reg ---
  const int orow = row0 + 16 * w + 4 * q;
#pragma unroll
  for (int ct = 0; ct < 4; ++ct)
#pragma unroll
    for (int rr = 0; rr < 4; ++rr)
      logits[(size_t)(orow + rr) * E + 16 * ct + r] = acc[ct][rr];
}

// ---------------------------------------------------------------------------
// Kernel 2: per-row softmax + top-2 (+renorm). One wave per row, lane=expert.
// ---------------------------------------------------------------------------
__global__ __launch_bounds__(256) void router_topk(const float* __restrict__ logits,
                                                   float* __restrict__ topw,
                                                   float* __restrict__ topi) {
  const int tid  = threadIdx.x;
  const int lane = tid & 63;
  const int row  = blockIdx.x * 4 + (tid >> 6);

  const float x = logits[(size_t)row * E + lane];

  float m = x;
#pragma unroll
  for (int off = 32; off; off >>= 1) m = fmaxf(m, __shfl_xor(m, off));
  const float p = expf(x - m);
  float s = p;
#pragma unroll
  for (int off = 32; off; off >>= 1) s += __shfl_xor(s, off);
  const float prob = p / s;

  float v1 = prob; int i1 = lane;
#pragma unroll
  for (int off = 32; off; off >>= 1) {
    const float ov = __shfl_xor(v1, off);
    const int   oi = __shfl_xor(i1, off);
    if (ov > v1 || (ov == v1 && oi < i1)) { v1 = ov; i1 = oi; }
  }
  float v2 = (lane == i1) ? -1.0f : prob; int i2 = lane;
#pragma unroll
  for (int off = 32; off; off >>= 1) {
    const float ov = __shfl_xor(v2, off);
    const int   oi = __shfl_xor(i2, off);
    if (ov > v2 || (ov == v2 && oi < i2)) { v2 = ov; i2 = oi; }
  }

  if (lane == 0) {
    const float sum = v1 + v2;
    topw[(size_t)row * 2 + 0] = v1 / sum;
    topw[(size_t)row * 2 + 1] = v2 / sum;
    topi[(size_t)row * 2 + 0] = (float)i1;
    topi[(size_t)row * 2 + 1] = (float)i2;
  }
}

extern "C" void kernel_launch(void* const* d_in, const int* in_sizes, int n_in,
                              void* d_out, int out_size, void* d_ws, size_t ws_size,
                              hipStream_t stream) {
  const float* H = (const float*)d_in[0];  // [16384, 4096] fp32
  const float* W = (const float*)d_in[1];  // [64, 4096] fp32

  float* out    = (float*)d_out;
  float* topw   = out;                       // [16384, 2]
  float* logits = out + (size_t)T * 2;       // [16384, 64]
  float* topi   = logits + (size_t)T * E;    // [16384, 2] (indices as float)

  short* wimg = (short*)d_ws;                // needs 1 MiB of ws

  wprep<<<256, 256, 0, stream>>>(W, wimg);
  router_gemm<<<T / 64, 256, 0, stream>>>(H, wimg, logits);
  router_topk<<<T / 4, 256, 0, stream>>>(logits, topw, topi);
}